// Round 8
// baseline (386.945 us; speedup 1.0000x reference)
//
#include <hip/hip_runtime.h>
#include <cstddef>

// Problem constants: B=8, C=512, N=4096, M=1024. Inputs f32, output f32.
#define Bn 8
#define Cd 512
#define Nn 4096
#define Mm 1024

typedef __attribute__((ext_vector_type(8))) short s8v;
typedef __attribute__((ext_vector_type(4))) float v4f;
typedef __attribute__((ext_vector_type(16))) float v16f;

__device__ __forceinline__ float b2f(unsigned short u) {
    union { unsigned int i; float f; } v; v.i = ((unsigned int)u) << 16; return v.f;
}
__device__ __forceinline__ unsigned short f2b(float f) {
    union { float f; unsigned int i; } v; v.f = f;
    unsigned int x = v.i;
    unsigned int r = (x + 0x7FFFu + ((x >> 16) & 1u)) >> 16;  // RNE
    return (unsigned short)r;
}
__device__ __forceinline__ unsigned int f2b2(float lo, float hi) {
    return (unsigned int)f2b(lo) | ((unsigned int)f2b(hi) << 16);
}
__device__ __forceinline__ v4f mfma16(s8v a, s8v b, v4f c) {
    return __builtin_amdgcn_mfma_f32_16x16x32_bf16(a, b, c, 0, 0, 0);
}
__device__ __forceinline__ v16f mfma32(s8v a, s8v b, v16f c) {
    return __builtin_amdgcn_mfma_f32_32x32x16_bf16(a, b, c, 0, 0, 0);
}

// ---------------------------------------------------------------------------
// convwf: W f32[512][512] -> bf16 MFMA A-fragment tiles.
// Wf[wsel][((o16*16 + cstep)*64 + lane)*8 + e]; readers get wave-uniform-base
// + lane*16B (coalesced 1KiB per fragment load).
// ---------------------------------------------------------------------------
__global__ __launch_bounds__(256) void convwf(const float* __restrict__ Wq, const float* __restrict__ Wk,
                                              const float* __restrict__ Wv, const float* __restrict__ Ws,
                                              unsigned short* __restrict__ Wf) {
    const float* S = (blockIdx.y == 0) ? Wq : (blockIdx.y == 1) ? Wk : (blockIdx.y == 2) ? Wv : Ws;
    const int o16 = blockIdx.x;            // 0..31
    const int t = threadIdx.x;
    const int l = t & 63, sub = t >> 6;
    const int lq = l & 15, quad = l >> 4;
    unsigned short* dst = Wf + (size_t)blockIdx.y * 262144;
#pragma unroll
    for (int rep = 0; rep < 4; ++rep) {
        int cstep = sub * 4 + rep;         // 0..15
        const float* src = S + (size_t)(o16 * 16 + lq) * Cd + cstep * 32 + quad * 8;
        float4 va = *(const float4*)(src);
        float4 vb = *(const float4*)(src + 4);
        union { ushort4 h[2]; uint4 q; } pk;
        pk.h[0].x = f2b(va.x); pk.h[0].y = f2b(va.y); pk.h[0].z = f2b(va.z); pk.h[0].w = f2b(va.w);
        pk.h[1].x = f2b(vb.x); pk.h[1].y = f2b(vb.y); pk.h[1].z = f2b(vb.z); pk.h[1].w = f2b(vb.w);
        *(uint4*)(dst + ((size_t)(o16 * 16 + cstep) * 64 + l) * 8) = pk.q;
    }
}

// ---------------------------------------------------------------------------
// gemm_kv: fused transpose + K/V GEMM (merges convx(down)+gemm4<0>).
// Block = (b, 32 m-rows, o-half), 256 thr / 4 waves. Prologue stages
// down[b][:, m0..m0+32] f32 -> bf16 swizzled LDS tile [32 m][64 units]
// (unit u of row m at u^(m&15); pair-c u32 writes). K-loop: 16 steps, NO
// inner barriers (tile resident), W A-frags coalesced from Wf, 16 mfma16
// per wave per step. Epilogue stores Kf (direct) / Vf (per-wave transpose)
// fragments, layouts matching the attn reader:
//   Kf[((mt*32+kb)*64 + (m&31)+32*((c>>3)&1))*8 + (c&7)]
//   Vf[((ct*64+mb)*64 + (c&31)+32*((m>>3)&1))*8 + (m&7)]
// ---------------------------------------------------------------------------
__global__ __launch_bounds__(256, 2) void gemm_kv(const unsigned short* __restrict__ Wf,
                                                  const float* __restrict__ down,
                                                  unsigned short* __restrict__ Kf,
                                                  unsigned short* __restrict__ Vf) {
    __shared__ __align__(16) unsigned char raw[37888];   // Xs 32KB + Vst 4x1280
    const int t = threadIdx.x;
    const int l = t & 63, w = t >> 6, lq = t & 15, quad = (t >> 4) & 3;
    const int bid = blockIdx.x;
    const int b = bid & 7, mt = (bid >> 3) & 31, half = bid >> 8;
    const int m0 = mt * 32;
    const float* db = down + (size_t)b * Cd * Mm + m0;
    const unsigned short* W1f = Wf + (size_t)1 * 262144 + (size_t)l * 8;   // Wk
    const unsigned short* W2f = Wf + (size_t)2 * 262144 + (size_t)l * 8;   // Wv

    // ---- stage down rows -> bf16 swizzled tile (pair-c u32 writes) ----
    {
#pragma unroll
        for (int rep = 0; rep < 8; ++rep) {
            int u = rep * 256 + t;             // 2048 units: 256 c2 x 8 m4-groups
            int c2 = u >> 3, m4 = (u & 7) * 4;
            float4 a = *(const float4*)(db + (size_t)(2 * c2) * Mm + m4);
            float4 c = *(const float4*)(db + (size_t)(2 * c2 + 1) * Mm + m4);
            int cu = c2 >> 2, sb = (c2 & 3) * 4;
            float av[4] = {a.x, a.y, a.z, a.w};
            float cv[4] = {c.x, c.y, c.z, c.w};
#pragma unroll
            for (int j = 0; j < 4; ++j) {
                int m = m4 + j;
                *(unsigned int*)(raw + ((m * 64 + (cu ^ (m & 15))) << 4) + sb) = f2b2(av[j], cv[j]);
            }
        }
    }
    __syncthreads();

    v4f acc1[4][2], acc2[4][2];
#pragma unroll
    for (int i = 0; i < 4; ++i)
#pragma unroll
        for (int nt = 0; nt < 2; ++nt) {
            acc1[i][nt] = (v4f){0.f, 0.f, 0.f, 0.f};
            acc2[i][nt] = (v4f){0.f, 0.f, 0.f, 0.f};
        }

    for (int step = 0; step < 16; ++step) {
        s8v a1[4], a2[4];
#pragma unroll
        for (int i = 0; i < 4; ++i) {
            int o16 = half * 16 + w * 4 + i;
            a1[i] = *(const s8v*)(W1f + ((size_t)(o16 * 16 + step) << 9));
            a2[i] = *(const s8v*)(W2f + ((size_t)(o16 * 16 + step) << 9));
        }
        s8v bf0 = *(const s8v*)(raw + ((lq * 64 + ((step * 4 + quad) ^ lq)) << 4));
        s8v bf1 = *(const s8v*)(raw + (((lq + 16) * 64 + ((step * 4 + quad) ^ lq)) << 4));
#pragma unroll
        for (int i = 0; i < 4; ++i) {
            acc1[i][0] = mfma16(a1[i], bf0, acc1[i][0]);
            acc1[i][1] = mfma16(a1[i], bf1, acc1[i][1]);
            acc2[i][0] = mfma16(a2[i], bf0, acc2[i][0]);
            acc2[i][1] = mfma16(a2[i], bf1, acc2[i][1]);
        }
    }
    __syncthreads();

    // ---- acc1 (K) -> Kf fragments, direct from acc ----
    const int hq = quad >> 1, ebase = (quad & 1) * 4;
    {
        unsigned short* Kb = Kf + (size_t)b * Mm * Cd;
#pragma unroll
        for (int i = 0; i < 4; ++i) {
            int kb = half * 16 + w * 4 + i;
#pragma unroll
            for (int nt = 0; nt < 2; ++nt) {
                int lf = (nt * 16 + lq) + 32 * hq;
                ushort4 v;
                v.x = f2b(acc1[i][nt][0]); v.y = f2b(acc1[i][nt][1]);
                v.z = f2b(acc1[i][nt][2]); v.w = f2b(acc1[i][nt][3]);
                *(ushort4*)(Kb + ((size_t)(mt * 32 + kb) * 64 + lf) * 8 + ebase) = v;
            }
        }
    }
    // ---- acc2 (V) -> Vf fragments via per-wave LDS transpose ----
    short (*Vst)[40] = reinterpret_cast<short(*)[40]>(raw + 32768 + w * 1280);   // [16][40]
    unsigned short* Vb0 = Vf + (size_t)b * Cd * Mm;
#pragma unroll
    for (int i = 0; i < 4; ++i) {
        int o16 = half * 16 + w * 4 + i;
#pragma unroll
        for (int nt = 0; nt < 2; ++nt)
#pragma unroll
            for (int r = 0; r < 4; ++r)
                Vst[quad * 4 + r][nt * 16 + lq] = (short)f2b(acc2[i][nt][r]);
        // same-wave ds ordering -> no barrier needed
        int c_abs = o16 * 16 + (l >> 2);
        int m8 = l & 3;
        int ct = c_abs >> 5, mb = (m0 >> 4) + (m8 >> 1);
        int lf = (c_abs & 31) + 32 * (m8 & 1);
        uint4 v = *(const uint4*)(&Vst[l >> 2][m8 * 8]);
        *(uint4*)(Vb0 + ((size_t)(ct * 64 + mb) * 64 + lf) * 8) = v;
    }
}

// ---------------------------------------------------------------------------
// MFMA GEMM (legacy, fallback path only). MODE 0: f32 store. MODE 2: bf16 D^T.
// ---------------------------------------------------------------------------
template <int MODE>
__global__ __launch_bounds__(256) void gemm_mfma(const float* __restrict__ W,
                                                 const float* __restrict__ X,
                                                 float* __restrict__ Yf,
                                                 unsigned short* __restrict__ Yb,
                                                 int Nx) {
    __shared__ short Xs[64][40];
    __shared__ short Tt[16][72];
    const int t = threadIdx.x;
    const int w = t >> 6, lq = t & 15, quad = (t >> 4) & 3;
    const int b = blockIdx.z, o0 = blockIdx.y * 64, n0 = blockIdx.x * 64;
    const float* Xb = X + (size_t)b * Cd * Nx;
    const float* Wrow = W + (size_t)(o0 + w * 16 + lq) * Cd;

    v4f acc[4];
#pragma unroll
    for (int i = 0; i < 4; ++i) acc[i] = (v4f){0.f, 0.f, 0.f, 0.f};

    for (int c0 = 0; c0 < Cd; c0 += 32) {
#pragma unroll
        for (int p = 0; p < 2; ++p) {
            int i = t + p * 256;
            int c = i >> 4;
            int n4 = (i & 15) * 4;
            float4 x = *(const float4*)(Xb + (size_t)(c0 + c) * Nx + n0 + n4);
            Xs[n4 + 0][c] = (short)f2b(x.x); Xs[n4 + 1][c] = (short)f2b(x.y);
            Xs[n4 + 2][c] = (short)f2b(x.z); Xs[n4 + 3][c] = (short)f2b(x.w);
        }
        union { unsigned short h[8]; s8v s; } af;
        {
            float4 wa = *(const float4*)(Wrow + c0 + quad * 8);
            float4 wb = *(const float4*)(Wrow + c0 + quad * 8 + 4);
            af.h[0] = f2b(wa.x); af.h[1] = f2b(wa.y); af.h[2] = f2b(wa.z); af.h[3] = f2b(wa.w);
            af.h[4] = f2b(wb.x); af.h[5] = f2b(wb.y); af.h[6] = f2b(wb.z); af.h[7] = f2b(wb.w);
        }
        __syncthreads();
#pragma unroll
        for (int nt = 0; nt < 4; ++nt) {
            s8v bf = *(const s8v*)(&Xs[nt * 16 + lq][quad * 8]);
            acc[nt] = mfma16(af.s, bf, acc[nt]);
        }
        __syncthreads();
    }

    if (MODE == 0) {
#pragma unroll
        for (int nt = 0; nt < 4; ++nt)
#pragma unroll
            for (int r = 0; r < 4; ++r) {
                int o = o0 + w * 16 + quad * 4 + r;
                int n = n0 + nt * 16 + lq;
                Yf[((size_t)b * Cd + o) * Nx + n] = acc[nt][r];
            }
    } else {
#pragma unroll
        for (int nt = 0; nt < 4; ++nt) {
#pragma unroll
            for (int r = 0; r < 4; ++r)
                Tt[lq][w * 16 + quad * 4 + r] = (short)f2b(acc[nt][r]);
            __syncthreads();
            int nrow = t >> 4, o4 = (t & 15) * 4;
            ushort4 val = *(const ushort4*)(&Tt[nrow][o4]);
            *(ushort4*)(Yb + ((size_t)b * Nx + n0 + nt * 16 + nrow) * Cd + o0 + o4) = val;
            __syncthreads();
        }
    }
}

// ---------------------------------------------------------------------------
// attn_f: fused Q-projection + skip-projection + flash attention.
// Round-8 changes vs round 7:
//  - staging writes pair-c u32 (dword-aligned) instead of scalar b16:
//    halves write count, kills sub-dword same-bank serialization.
//  - skip kept in REGISTERS (ask[4][4]) through the main loop; added into
//    the OtW epilogue transpose, final out write is a PURE STORE
//    (saves 64MB skip store + 64MB RMW read; WRITE_SIZE ~131->~66MB).
// ---------------------------------------------------------------------------
__global__ __launch_bounds__(512, 2) void attn_f(const float* __restrict__ up,
                                                 const unsigned short* __restrict__ Wf,
                                                 const unsigned short* __restrict__ Kf,
                                                 const unsigned short* __restrict__ Vf,
                                                 float* __restrict__ out) {
    __shared__ __align__(16) unsigned char Ls[104192];
    unsigned char* Lq = Ls;                                   // Xu then Q: 64x512 bf16 swizzled (65536)
    unsigned short* Pb = (unsigned short*)(Ls + 65536);       // [64][264] bf16 (33792)
    float* pmaxS  = (float*)(Ls + 99328);                     // [64][8]
    float* psumS  = (float*)(Ls + 101376);                    // [64][8]
    float* muS    = (float*)(Ls + 103424);                    // [64]
    float* ssumS  = (float*)(Ls + 103680);                    // [64]
    float* alphaS = (float*)(Ls + 103936);                    // [64]
    float* OtA    = (float*)Ls;                               // epilogue alias [8][32][36] f32

    const int t = threadIdx.x;
    const int l = t & 63, w = t >> 6;          // 8 waves
    const int lcol = l & 31, lhalf = l >> 5;
    const int lq = l & 15, quad = (l >> 4) & 3;
    const int bid = blockIdx.x;
    const int b = bid & 7, n0 = (bid >> 3) * 64;

    v4f ask[4][4];   // skip fragments, live through the whole kernel

    // ---- (1) stage up rows -> Xu bf16 swizzled (pair-c u32 writes) ----
    {
        const float* ub = up + (size_t)b * Cd * Nn + n0;
#pragma unroll
        for (int it = 0; it < 8; ++it) {
            int u = it * 512 + t;              // 4096 units: 256 c2 x 16 n4-groups
            int c2 = u >> 4, n4 = (u & 15) * 4;
            float4 a = *(const float4*)(ub + (size_t)(2 * c2) * Nn + n4);
            float4 c = *(const float4*)(ub + (size_t)(2 * c2 + 1) * Nn + n4);
            int cu = c2 >> 2, sb = (c2 & 3) * 4;
            float av[4] = {a.x, a.y, a.z, a.w};
            float cv[4] = {c.x, c.y, c.z, c.w};
#pragma unroll
            for (int j = 0; j < 4; ++j) {
                int n = n4 + j;
                *(unsigned int*)(Lq + ((n * 64 + (cu ^ (n & 15))) << 4) + sb) = f2b2(av[j], cv[j]);
            }
        }
    }
    __syncthreads();

    // ---- (2) Q + skip prologue: wave w owns o = w*64 .. w*64+63 ----
    {
        v4f aq[4][4];
#pragma unroll
        for (int oi = 0; oi < 4; ++oi)
#pragma unroll
            for (int ni = 0; ni < 4; ++ni) {
                aq[oi][ni] = (v4f){0.f, 0.f, 0.f, 0.f};
                ask[oi][ni] = (v4f){0.f, 0.f, 0.f, 0.f};
            }
        const unsigned short* WqF = Wf + (size_t)l * 8;                    // Wf[0] = Wq
        const unsigned short* WsF = Wf + (size_t)3 * 262144 + (size_t)l * 8;  // Wf[3] = Wskip
        for (int step = 0; step < 16; ++step) {
            s8v a1[4], a2[4];
#pragma unroll
            for (int oi = 0; oi < 4; ++oi)
                a1[oi] = *(const s8v*)(WqF + ((size_t)((w * 4 + oi) * 16 + step) << 9));
#pragma unroll
            for (int oi = 0; oi < 4; ++oi)
                a2[oi] = *(const s8v*)(WsF + ((size_t)((w * 4 + oi) * 16 + step) << 9));
#pragma unroll
            for (int ni = 0; ni < 4; ++ni) {
                int n = ni * 16 + lq;          // n&15 == lq
                s8v bf = *(const s8v*)(Lq + ((n * 64 + ((step * 4 + quad) ^ lq)) << 4));
#pragma unroll
                for (int oi = 0; oi < 4; ++oi) {
                    aq[oi][ni] = mfma16(a1[oi], bf, aq[oi][ni]);
                    ask[oi][ni] = mfma16(a2[oi], bf, ask[oi][ni]);
                }
            }
        }
        __syncthreads();   // all Xu reads complete before overwrite
        // Q -> Lq (overwrite Xu), swizzled bf16, 8B per (oi,ni)
#pragma unroll
        for (int oi = 0; oi < 4; ++oi)
#pragma unroll
            for (int ni = 0; ni < 4; ++ni) {
                int n = ni * 16 + lq;
                int cu = w * 8 + oi * 2 + (quad >> 1);
                ushort4 pk;
                pk.x = f2b(aq[oi][ni][0]); pk.y = f2b(aq[oi][ni][1]);
                pk.z = f2b(aq[oi][ni][2]); pk.w = f2b(aq[oi][ni][3]);
                *(ushort4*)(Lq + ((n * 64 + (cu ^ lq)) << 4) + (quad & 1) * 8) = pk;
            }
    }
    if (t < 64) { muS[t] = -1e30f; ssumS[t] = 0.f; }

    v16f o_acc[2][2];
#pragma unroll
    for (int nh = 0; nh < 2; ++nh)
#pragma unroll
        for (int ti = 0; ti < 2; ++ti)
#pragma unroll
            for (int r = 0; r < 16; ++r) o_acc[nh][ti][r] = 0.f;
    __syncthreads();

    const unsigned short* Kfb = Kf + (size_t)b * Mm * Cd + (size_t)l * 8;
    const unsigned short* Vfb = Vf + (size_t)b * Cd * Mm + (size_t)l * 8;
    const int q0 = lcol * 64, q1 = (lcol + 32) * 64;
    const int swz = lcol & 15;
    const float sc = 0.04419417382415922f;   // 1/sqrt(512)

    for (int m0 = 0; m0 < Mm; m0 += 256) {
        v16f st0, st1;
#pragma unroll
        for (int r = 0; r < 16; ++r) { st0[r] = 0.f; st1[r] = 0.f; }
        const unsigned short* kp = Kfb + (size_t)(((m0 >> 5) + w) * 32) * 512;
#pragma unroll
        for (int kb8 = 0; kb8 < 4; ++kb8) {
            uint4 ka[8];
#pragma unroll
            for (int j = 0; j < 8; ++j) ka[j] = *(const uint4*)(kp + (size_t)(kb8 * 8 + j) * 512);
            __builtin_amdgcn_s_setprio(1);
#pragma unroll
            for (int j = 0; j < 8; ++j) {
                int kb = kb8 * 8 + j;
                int uo = (kb * 2 + lhalf) ^ swz;
                s8v qf0 = *(const s8v*)(Lq + ((q0 + uo) << 4));
                s8v qf1 = *(const s8v*)(Lq + ((q1 + uo) << 4));
                union { uint4 u; s8v s; } av; av.u = ka[j];
                st0 = mfma32(av.s, qf0, st0);
                st1 = mfma32(av.s, qf1, st1);
            }
            __builtin_amdgcn_s_setprio(0);
        }
        uint4 v0p[8];
        {
            const unsigned short* vc = Vfb + (size_t)((w * 2) * 64 + (m0 >> 4)) * 512;
#pragma unroll
            for (int j = 0; j < 8; ++j) v0p[j] = *(const uint4*)(vc + (size_t)j * 512);
        }
#pragma unroll
        for (int r = 0; r < 16; ++r) { st0[r] *= sc; st1[r] *= sc; }
        float tm0 = st0[0], tm1 = st1[0];
#pragma unroll
        for (int r = 1; r < 16; ++r) { tm0 = fmaxf(tm0, st0[r]); tm1 = fmaxf(tm1, st1[r]); }
        tm0 = fmaxf(tm0, __shfl_xor(tm0, 32));
        tm1 = fmaxf(tm1, __shfl_xor(tm1, 32));
        if (l < 32) {
            pmaxS[l * 8 + w] = tm0;
            pmaxS[(l + 32) * 8 + w] = tm1;
        }
        __syncthreads();   // S1
        {
            int row = t >> 3, p = t & 7;
            float v = pmaxS[row * 8 + p];
            v = fmaxf(v, __shfl_xor(v, 1));
            v = fmaxf(v, __shfl_xor(v, 2));
            v = fmaxf(v, __shfl_xor(v, 4));
            if (p == 0) {
                float mold = muS[row];
                float mx = fmaxf(mold, v);
                alphaS[row] = __expf(mold - mx);
                muS[row] = mx;
            }
        }
        __syncthreads();   // S2
        {
            float mx0 = muS[lcol], mx1 = muS[lcol + 32];
            float e0[16], e1[16], rs0 = 0.f, rs1 = 0.f;
#pragma unroll
            for (int r = 0; r < 16; ++r) {
                e0[r] = __expf(st0[r] - mx0); rs0 += e0[r];
                e1[r] = __expf(st1[r] - mx1); rs1 += e1[r];
            }
            rs0 += __shfl_xor(rs0, 32);
            rs1 += __shfl_xor(rs1, 32);
            if (l < 32) {
                psumS[l * 8 + w] = rs0;
                psumS[(l + 32) * 8 + w] = rs1;
            }
#pragma unroll
            for (int rg = 0; rg < 4; ++rg) {
                ushort4 pk0, pk1;
                pk0.x = f2b(e0[rg * 4 + 0]); pk0.y = f2b(e0[rg * 4 + 1]);
                pk0.z = f2b(e0[rg * 4 + 2]); pk0.w = f2b(e0[rg * 4 + 3]);
                pk1.x = f2b(e1[rg * 4 + 0]); pk1.y = f2b(e1[rg * 4 + 1]);
                pk1.z = f2b(e1[rg * 4 + 2]); pk1.w = f2b(e1[rg * 4 + 3]);
                *(ushort4*)(Pb + lcol * 264 + w * 32 + 8 * rg + 4 * lhalf) = pk0;
                *(ushort4*)(Pb + (lcol + 32) * 264 + w * 32 + 8 * rg + 4 * lhalf) = pk1;
            }
        }
        __syncthreads();   // S3
        {
            int row = t >> 3, p = t & 7;
            float v = psumS[row * 8 + p];
            v += __shfl_xor(v, 1);
            v += __shfl_xor(v, 2);
            v += __shfl_xor(v, 4);
            if (p == 0) ssumS[row] = ssumS[row] * alphaS[row] + v;
        }

        float ar0[16], ar1[16];
#pragma unroll
        for (int r = 0; r < 16; ++r) {
            int crow = (r & 3) + 8 * (r >> 2) + 4 * lhalf;
            ar0[r] = alphaS[crow];
            ar1[r] = alphaS[32 + crow];
        }
#pragma unroll
        for (int ti = 0; ti < 2; ++ti)
#pragma unroll
            for (int r = 0; r < 16; ++r) {
                o_acc[0][ti][r] *= ar0[r];
                o_acc[1][ti][r] *= ar1[r];
            }

#pragma unroll
        for (int h = 0; h < 2; ++h) {
            s8v pA0[8], pA1[8];
#pragma unroll
            for (int j = 0; j < 8; ++j) {
                pA0[j] = *(const s8v*)(Pb + lcol * 264 + (h * 8 + j) * 16 + lhalf * 8);
                pA1[j] = *(const s8v*)(Pb + (lcol + 32) * 264 + (h * 8 + j) * 16 + lhalf * 8);
            }
#pragma unroll
            for (int ti = 0; ti < 2; ++ti) {
                uint4 vb[8];
                if (h == 0 && ti == 0) {
#pragma unroll
                    for (int j = 0; j < 8; ++j) vb[j] = v0p[j];
                } else {
                    const unsigned short* vc = Vfb + (size_t)((w * 2 + ti) * 64 + (m0 >> 4) + h * 8) * 512;
#pragma unroll
                    for (int j = 0; j < 8; ++j) vb[j] = *(const uint4*)(vc + (size_t)j * 512);
                }
                __builtin_amdgcn_s_setprio(1);
#pragma unroll
                for (int j = 0; j < 8; ++j) {
                    union { uint4 u; s8v s; } bv; bv.u = vb[j];
                    o_acc[0][ti] = mfma32(pA0[j], bv.s, o_acc[0][ti]);
                    o_acc[1][ti] = mfma32(pA1[j], bv.s, o_acc[1][ti]);
                }
                __builtin_amdgcn_s_setprio(0);
            }
        }
        __syncthreads();
    }

    // ---- epilogue: out[b][c][n0..n0+63] = skip + O/l (PURE store) ----
    // wave w's o_acc covers c in [w*64, w*64+64) == its ask o-range.
    float inv0[16], inv1[16];
#pragma unroll
    for (int r = 0; r < 16; ++r) {
        int crow = (r & 3) + 8 * (r >> 2) + 4 * lhalf;
        inv0[r] = 1.0f / ssumS[crow];
        inv1[r] = 1.0f / ssumS[32 + crow];
    }
    float* OtW = OtA + w * 32 * 36;
#pragma unroll
    for (int nh = 0; nh < 2; ++nh)
#pragma unroll
        for (int ti = 0; ti < 2; ++ti) {
            // pass 1: O/l into OtW (same-wave DS ordering throughout)
#pragma unroll
            for (int r = 0; r < 16; ++r) {
                int crow = (r & 3) + 8 * (r >> 2) + 4 * lhalf;
                OtW[lcol * 36 + crow] = o_acc[nh][ti][r] * (nh ? inv1[r] : inv0[r]);
            }
            // pass 2: add skip fragments for this (c,n) window; lane-exclusive
            // addresses (quad,lq distinct), wave-ordered DS => no race.
#pragma unroll
            for (int oi2 = 0; oi2 < 2; ++oi2)
#pragma unroll
                for (int ni2 = 0; ni2 < 2; ++ni2) {
                    int oi = ti * 2 + oi2, ni = nh * 2 + ni2;
#pragma unroll
                    for (int r = 0; r < 4; ++r) {
                        int cloc2 = oi2 * 16 + quad * 4 + r;
                        int nloc = ni2 * 16 + lq;
                        OtW[cloc2 * 36 + nloc] += ask[oi][ni][r];
                    }
                }
            // pass 3: pure store
            int cloc = l >> 1, half = l & 1;
            int cabs = (w * 2 + ti) * 32 + cloc;
            const float* src = OtW + cloc * 36 + half * 16;
            float* op = out + ((size_t)b * Cd + cabs) * Nn + n0 + nh * 32 + half * 16;
#pragma unroll
            for (int j = 0; j < 4; ++j)
                *(float4*)(op + j * 4) = *(const float4*)(src + j * 4);
        }
}

// ---------------------------------------------------------------------------
// Fallback VALU attention (proven) for small ws_size.
// ---------------------------------------------------------------------------
__device__ __forceinline__ float u2lo(unsigned int u) {
    union { unsigned int i; float f; } v; v.i = u << 16; return v.f;
}
__device__ __forceinline__ float u2hi(unsigned int u) {
    union { unsigned int i; float f; } v; v.i = u & 0xFFFF0000u; return v.f;
}

__global__ __launch_bounds__(256) void attn_k(const float* __restrict__ up,
                                              const float* __restrict__ Wq,
                                              const unsigned short* __restrict__ Ktb,
                                              const unsigned short* __restrict__ Vtb,
                                              float* __restrict__ out) {
    __shared__ float Qs[16][516];
    __shared__ __align__(16) unsigned char Sraw[24576];
    unsigned short (*Us)[16]  = reinterpret_cast<unsigned short(*)[16]>(Sraw);
    unsigned short (*Wt)[512] = reinterpret_cast<unsigned short(*)[512]>(Sraw + 16384);
    float (*Ps)[65] = reinterpret_cast<float(*)[65]>(Sraw);
    float* mu_s     = reinterpret_cast<float*>(Sraw + 4160);
    float* ssum_s   = reinterpret_cast<float*>(Sraw + 4224);
    float* alpha_s  = reinterpret_cast<float*>(Sraw + 4288);

    const int t = threadIdx.x;
    const int b = blockIdx.y;
    const int n0 = blockIdx.x * 16;
    const int row = t & 15;
    const int grp = t >> 4;

    for (int i = t; i < Cd * 16; i += 256) {
        int c = i >> 4, r = i & 15;
        Us[c][r] = f2b(up[((size_t)b * Cd + c) * Nn + n0 + r]);
    }
    __syncthreads();

    float acc[32];
#pragma unroll
    for (int j = 0; j < 32; ++j) acc[j] = 0.f;

    for (int k0 = 0; k0 < Cd; k0 += 8) {
        for (int i = t; i < 1024; i += 256) {
            int oc = i >> 1;
            int kc = (i & 1) * 4;
            float4 wv = *(const float4*)(Wq + (size_t)oc * Cd + k0 + kc);
            Wt[kc + 0][oc] = f2b(wv.x); Wt[kc + 1][oc] = f2b(wv.y);
            Wt[kc + 2][oc] = f2b(wv.z); Wt[kc + 3][oc] = f2b(wv.w);
        }
        __syncthreads();
#pragma unroll
        for (int k = 0; k < 8; ++k) {
            float u = b2f(Us[k0 + k][row]);
            const ushort4* wr = (const ushort4*)(&Wt[k][grp * 32]);
#pragma unroll
            for (int j4 = 0; j4 < 8; ++j4) {
                ushort4 wv = wr[j4];
                acc[j4 * 4 + 0] += u * b2f(wv.x);
                acc[j4 * 4 + 1] += u * b2f(wv.y);
                acc[j4 * 4 + 2] += u * b2f(wv.z);
                acc[j4 * 4 + 3] += u * b2f(wv.w);
            }
        }
        __syncthreads();
    }

    const float scale = 0.04419417382415922f;
#pragma unroll
    for (int j = 0; j < 32; ++j) Qs[row][grp * 32 + j] = acc[j] * scale;
    if (t < 16) { mu_s[t] = -1e30f; ssum_s[t] = 0.f; }
#pragma unroll
    for (int j = 0; j < 32; ++j) acc[j] = 0.f;
    __syncthreads();

    const float4* qr = (const float4*)(&Qs[row][0]);

    for (int m0 = 0; m0 < Mm; m0 += 64) {
        {
            int mb = m0 + grp * 4;
            const uint4* K0 = (const uint4*)(Ktb + ((size_t)b * Mm + mb + 0) * Cd);
            const uint4* K1 = (const uint4*)(Ktb + ((size_t)b * Mm + mb + 1) * Cd);
            const uint4* K2 = (const uint4*)(Ktb + ((size_t)b * Mm + mb + 2) * Cd);
            const uint4* K3 = (const uint4*)(Ktb + ((size_t)b * Mm + mb + 3) * Cd);
            float a0 = 0.f, a1 = 0.f, a2 = 0.f, a3 = 0.f;
#pragma unroll 4
            for (int c8 = 0; c8 < Cd / 8; ++c8) {
                float4 qa = qr[2 * c8], qb = qr[2 * c8 + 1];
                uint4 k0v = K0[c8], k1v = K1[c8], k2v = K2[c8], k3v = K3[c8];
                a0 += qa.x * u2lo(k0v.x) + qa.y * u2hi(k0v.x) + qa.z * u2lo(k0v.y) + qa.w * u2hi(k0v.y)
                    + qb.x * u2lo(k0v.z) + qb.y * u2hi(k0v.z) + qb.z * u2lo(k0v.w) + qb.w * u2hi(k0v.w);
                a1 += qa.x * u2lo(k1v.x) + qa.y * u2hi(k1v.x) + qa.z * u2lo(k1v.y) + qa.w * u2hi(k1v.y)
                    + qb.x * u2lo(k1v.z) + qb.y * u2hi(k1v.z) + qb.z * u2lo(k1v.w) + qb.w * u2hi(k1v.w);
                a2 += qa.x * u2lo(k2v.x) + qa.y * u2hi(k2v.x) + qa.z * u2lo(k2v.y) + qa.w * u2hi(k2v.y)
                    + qb.x * u2lo(k2v.z) + qb.y * u2hi(k2v.z) + qb.z * u2lo(k2v.w) + qb.w * u2hi(k2v.w);
                a3 += qa.x * u2lo(k3v.x) + qa.y * u2hi(k3v.x) + qa.z * u2lo(k3v.y) + qa.w * u2hi(k3v.y)
                    + qb.x * u2lo(k3v.z) + qb.y * u2hi(k3v.z) + qb.z * u2lo(k3v.w) + qb.w * u2hi(k3v.w);
            }
            Ps[row][grp * 4 + 0] = a0;
            Ps[row][grp * 4 + 1] = a1;
            Ps[row][grp * 4 + 2] = a2;
            Ps[row][grp * 4 + 3] = a3;
        }
        __syncthreads();
        if (t < 16) {
            float mold = mu_s[t];
            float mx = mold;
            for (int m = 0; m < 64; ++m) mx = fmaxf(mx, Ps[t][m]);
            float al = __expf(mold - mx);
            float s = ssum_s[t] * al;
            for (int m = 0; m < 64; ++m) {
                float p = __expf(Ps[t][m] - mx);
                Ps[t][m] = p;
                s += p;
            }
            mu_s[t] = mx; ssum_s[t] = s; alpha_s[t] = al;
        }
        __syncthreads();
        {
            float arr = alpha_s[row];
#pragma unroll
            for (int j = 0; j < 32; ++j) acc[j] *= arr;
            const unsigned short* Vbase = Vtb + (size_t)b * Mm * Cd + (size_t)grp * 32;
            for (int m = 0; m < 64; ++m) {
                float p = Ps[row][m];
                const uint4* vr = (const uint4*)(Vbase + (size_t)(m0 + m) * Cd);
#pragma unroll
                for (int j4 = 0; j4 < 4; ++j4) {
                    uint4 v = vr[j4];
                    acc[j4 * 8 + 0] += p * u2lo(v.x); acc[j4 * 8 + 1] += p * u2hi(v.x);
                    acc[j4 * 8 + 2] += p * u2lo(v.y); acc[j4 * 8 + 3] += p * u2hi(v.y);
                    acc[j4 * 8 + 4] += p * u2lo(v.z); acc[j4 * 8 + 5] += p * u2hi(v.z);
                    acc[j4 * 8 + 6] += p * u2lo(v.w); acc[j4 * 8 + 7] += p * u2hi(v.w);
                }
            }
        }
        __syncthreads();
    }

    float invv = 1.0f / ssum_s[row];
#pragma unroll
    for (int j = 0; j < 32; ++j) {
        int c = grp * 32 + j;
        size_t idx = ((size_t)b * Cd + c) * Nn + n0 + row;
        out[idx] = out[idx] + acc[j] * invv;
    }
}

// ---------------------------------------------------------------------------
extern "C" void kernel_launch(void* const* d_in, const int* in_sizes, int n_in,
                              void* d_out, int out_size, void* d_ws, size_t ws_size,
                              hipStream_t stream) {
    const float* up   = (const float*)d_in[0];
    const float* down = (const float*)d_in[1];
    const float* Wq   = (const float*)d_in[2];
    const float* Wk   = (const float*)d_in[3];
    const float* Wv   = (const float*)d_in[4];
    const float* Wsk  = (const float*)d_in[5];
    float* out = (float*)d_out;

    const size_t szK = (size_t)Bn * Mm * Cd;   // 4M bf16 elems (8 MiB)
    const size_t szW = (size_t)4 * Cd * Cd;    // 1M elems (2 MiB)

    if (ws_size >= (2 * szK + szW) * 2) {
        // 18 MiB path, 3 dispatches:
        // convwf -> gemm_kv (fused transpose+K/V) -> attn_f (Q+skip+attention).
        unsigned short* Kf = (unsigned short*)d_ws;
        unsigned short* Vf = Kf + szK;
        unsigned short* Wf = Vf + szK;
        convwf<<<dim3(32, 4), 256, 0, stream>>>(Wq, Wk, Wv, Wsk, Wf);
        gemm_kv<<<dim3(Bn * (Mm / 32) * 2), 256, 0, stream>>>(Wf, down, Kf, Vf);
        attn_f<<<dim3((Nn / 64) * Bn), 512, 0, stream>>>(up, Wf, Kf, Vf, out);
    } else {
        // Fallback (16 MiB ws): VALU attention.
        unsigned short* Ktb = (unsigned short*)d_ws;
        unsigned short* Vtb = Ktb + szK;
        gemm_mfma<2><<<dim3(Mm / 64, Cd / 64, Bn), 256, 0, stream>>>(Wk, down, nullptr, Ktb, Mm);
        gemm_mfma<2><<<dim3(Mm / 64, Cd / 64, Bn), 256, 0, stream>>>(Wv, down, nullptr, Vtb, Mm);
        gemm_mfma<0><<<dim3(Nn / 64, Cd / 64, Bn), 256, 0, stream>>>(Wsk, up, out, nullptr, Nn);
        attn_k<<<dim3(Nn / 16, Bn), 256, 0, stream>>>(up, Wq, Ktb, Vtb, out);
    }
}

// Round 9
// 272.946 us; speedup vs baseline: 1.4177x; 1.4177x over previous
//
#include <hip/hip_runtime.h>
#include <cstddef>

// Problem constants: B=8, C=512, N=4096, M=1024. Inputs f32, output f32.
#define Bn 8
#define Cd 512
#define Nn 4096
#define Mm 1024

typedef __attribute__((ext_vector_type(8))) short s8v;
typedef __attribute__((ext_vector_type(4))) float v4f;
typedef __attribute__((ext_vector_type(16))) float v16f;

__device__ __forceinline__ float b2f(unsigned short u) {
    union { unsigned int i; float f; } v; v.i = ((unsigned int)u) << 16; return v.f;
}
__device__ __forceinline__ unsigned short f2b(float f) {
    union { float f; unsigned int i; } v; v.f = f;
    unsigned int x = v.i;
    unsigned int r = (x + 0x7FFFu + ((x >> 16) & 1u)) >> 16;  // RNE
    return (unsigned short)r;
}
__device__ __forceinline__ unsigned int f2b2(float lo, float hi) {
    return (unsigned int)f2b(lo) | ((unsigned int)f2b(hi) << 16);
}
__device__ __forceinline__ v4f mfma16(s8v a, s8v b, v4f c) {
    return __builtin_amdgcn_mfma_f32_16x16x32_bf16(a, b, c, 0, 0, 0);
}
__device__ __forceinline__ v16f mfma32(s8v a, s8v b, v16f c) {
    return __builtin_amdgcn_mfma_f32_32x32x16_bf16(a, b, c, 0, 0, 0);
}

// ---------------------------------------------------------------------------
// convwf: W f32[512][512] -> bf16 MFMA A-fragment tiles.
// Wf[wsel][((o16*16 + cstep)*64 + lane)*8 + e]; readers get wave-uniform-base
// + lane*16B (coalesced 1KiB per fragment load).
// ---------------------------------------------------------------------------
__global__ __launch_bounds__(256) void convwf(const float* __restrict__ Wq, const float* __restrict__ Wk,
                                              const float* __restrict__ Wv, const float* __restrict__ Ws,
                                              unsigned short* __restrict__ Wf) {
    const float* S = (blockIdx.y == 0) ? Wq : (blockIdx.y == 1) ? Wk : (blockIdx.y == 2) ? Wv : Ws;
    const int o16 = blockIdx.x;            // 0..31
    const int t = threadIdx.x;
    const int l = t & 63, sub = t >> 6;
    const int lq = l & 15, quad = l >> 4;
    unsigned short* dst = Wf + (size_t)blockIdx.y * 262144;
#pragma unroll
    for (int rep = 0; rep < 4; ++rep) {
        int cstep = sub * 4 + rep;         // 0..15
        const float* src = S + (size_t)(o16 * 16 + lq) * Cd + cstep * 32 + quad * 8;
        float4 va = *(const float4*)(src);
        float4 vb = *(const float4*)(src + 4);
        union { ushort4 h[2]; uint4 q; } pk;
        pk.h[0].x = f2b(va.x); pk.h[0].y = f2b(va.y); pk.h[0].z = f2b(va.z); pk.h[0].w = f2b(va.w);
        pk.h[1].x = f2b(vb.x); pk.h[1].y = f2b(vb.y); pk.h[1].z = f2b(vb.z); pk.h[1].w = f2b(vb.w);
        *(uint4*)(dst + ((size_t)(o16 * 16 + cstep) * 64 + l) * 8) = pk.q;
    }
}

// ---------------------------------------------------------------------------
// gemm_kv: fused transpose + K/V GEMM (proven round 8 — kept unchanged).
// Block = (b, 32 m-rows, o-half), 256 thr / 4 waves. Stages down slice as
// bf16 swizzled resident LDS tile (pair-c u32 writes), 16-step MFMA loop with
// no inner barriers, Kf/Vf fragment epilogue matching the attn reader:
//   Kf[((mt*32+kb)*64 + (m&31)+32*((c>>3)&1))*8 + (c&7)]
//   Vf[((ct*64+mb)*64 + (c&31)+32*((m>>3)&1))*8 + (m&7)]
// ---------------------------------------------------------------------------
__global__ __launch_bounds__(256, 2) void gemm_kv(const unsigned short* __restrict__ Wf,
                                                  const float* __restrict__ down,
                                                  unsigned short* __restrict__ Kf,
                                                  unsigned short* __restrict__ Vf) {
    __shared__ __align__(16) unsigned char raw[37888];   // Xs 32KB + Vst 4x1280
    const int t = threadIdx.x;
    const int l = t & 63, w = t >> 6, lq = t & 15, quad = (t >> 4) & 3;
    const int bid = blockIdx.x;
    const int b = bid & 7, mt = (bid >> 3) & 31, half = bid >> 8;
    const int m0 = mt * 32;
    const float* db = down + (size_t)b * Cd * Mm + m0;
    const unsigned short* W1f = Wf + (size_t)1 * 262144 + (size_t)l * 8;   // Wk
    const unsigned short* W2f = Wf + (size_t)2 * 262144 + (size_t)l * 8;   // Wv

    // ---- stage down rows -> bf16 swizzled tile (pair-c u32 writes) ----
    {
#pragma unroll
        for (int rep = 0; rep < 8; ++rep) {
            int u = rep * 256 + t;             // 2048 units: 256 c2 x 8 m4-groups
            int c2 = u >> 3, m4 = (u & 7) * 4;
            float4 a = *(const float4*)(db + (size_t)(2 * c2) * Mm + m4);
            float4 c = *(const float4*)(db + (size_t)(2 * c2 + 1) * Mm + m4);
            int cu = c2 >> 2, sb = (c2 & 3) * 4;
            float av[4] = {a.x, a.y, a.z, a.w};
            float cv[4] = {c.x, c.y, c.z, c.w};
#pragma unroll
            for (int j = 0; j < 4; ++j) {
                int m = m4 + j;
                *(unsigned int*)(raw + ((m * 64 + (cu ^ (m & 15))) << 4) + sb) = f2b2(av[j], cv[j]);
            }
        }
    }
    __syncthreads();

    v4f acc1[4][2], acc2[4][2];
#pragma unroll
    for (int i = 0; i < 4; ++i)
#pragma unroll
        for (int nt = 0; nt < 2; ++nt) {
            acc1[i][nt] = (v4f){0.f, 0.f, 0.f, 0.f};
            acc2[i][nt] = (v4f){0.f, 0.f, 0.f, 0.f};
        }

    for (int step = 0; step < 16; ++step) {
        s8v a1[4], a2[4];
#pragma unroll
        for (int i = 0; i < 4; ++i) {
            int o16 = half * 16 + w * 4 + i;
            a1[i] = *(const s8v*)(W1f + ((size_t)(o16 * 16 + step) << 9));
            a2[i] = *(const s8v*)(W2f + ((size_t)(o16 * 16 + step) << 9));
        }
        s8v bf0 = *(const s8v*)(raw + ((lq * 64 + ((step * 4 + quad) ^ lq)) << 4));
        s8v bf1 = *(const s8v*)(raw + (((lq + 16) * 64 + ((step * 4 + quad) ^ lq)) << 4));
#pragma unroll
        for (int i = 0; i < 4; ++i) {
            acc1[i][0] = mfma16(a1[i], bf0, acc1[i][0]);
            acc1[i][1] = mfma16(a1[i], bf1, acc1[i][1]);
            acc2[i][0] = mfma16(a2[i], bf0, acc2[i][0]);
            acc2[i][1] = mfma16(a2[i], bf1, acc2[i][1]);
        }
    }
    __syncthreads();

    // ---- acc1 (K) -> Kf fragments, direct from acc ----
    const int hq = quad >> 1, ebase = (quad & 1) * 4;
    {
        unsigned short* Kb = Kf + (size_t)b * Mm * Cd;
#pragma unroll
        for (int i = 0; i < 4; ++i) {
            int kb = half * 16 + w * 4 + i;
#pragma unroll
            for (int nt = 0; nt < 2; ++nt) {
                int lf = (nt * 16 + lq) + 32 * hq;
                ushort4 v;
                v.x = f2b(acc1[i][nt][0]); v.y = f2b(acc1[i][nt][1]);
                v.z = f2b(acc1[i][nt][2]); v.w = f2b(acc1[i][nt][3]);
                *(ushort4*)(Kb + ((size_t)(mt * 32 + kb) * 64 + lf) * 8 + ebase) = v;
            }
        }
    }
    // ---- acc2 (V) -> Vf fragments via per-wave LDS transpose ----
    short (*Vst)[40] = reinterpret_cast<short(*)[40]>(raw + 32768 + w * 1280);   // [16][40]
    unsigned short* Vb0 = Vf + (size_t)b * Cd * Mm;
#pragma unroll
    for (int i = 0; i < 4; ++i) {
        int o16 = half * 16 + w * 4 + i;
#pragma unroll
        for (int nt = 0; nt < 2; ++nt)
#pragma unroll
            for (int r = 0; r < 4; ++r)
                Vst[quad * 4 + r][nt * 16 + lq] = (short)f2b(acc2[i][nt][r]);
        // same-wave ds ordering -> no barrier needed
        int c_abs = o16 * 16 + (l >> 2);
        int m8 = l & 3;
        int ct = c_abs >> 5, mb = (m0 >> 4) + (m8 >> 1);
        int lf = (c_abs & 31) + 32 * (m8 & 1);
        uint4 v = *(const uint4*)(&Vst[l >> 2][m8 * 8]);
        *(uint4*)(Vb0 + ((size_t)(ct * 64 + mb) * 64 + lf) * 8) = v;
    }
}

// ---------------------------------------------------------------------------
// MFMA GEMM (legacy, fallback path only). MODE 0: f32 store. MODE 2: bf16 D^T.
// ---------------------------------------------------------------------------
template <int MODE>
__global__ __launch_bounds__(256) void gemm_mfma(const float* __restrict__ W,
                                                 const float* __restrict__ X,
                                                 float* __restrict__ Yf,
                                                 unsigned short* __restrict__ Yb,
                                                 int Nx) {
    __shared__ short Xs[64][40];
    __shared__ short Tt[16][72];
    const int t = threadIdx.x;
    const int w = t >> 6, lq = t & 15, quad = (t >> 4) & 3;
    const int b = blockIdx.z, o0 = blockIdx.y * 64, n0 = blockIdx.x * 64;
    const float* Xb = X + (size_t)b * Cd * Nx;
    const float* Wrow = W + (size_t)(o0 + w * 16 + lq) * Cd;

    v4f acc[4];
#pragma unroll
    for (int i = 0; i < 4; ++i) acc[i] = (v4f){0.f, 0.f, 0.f, 0.f};

    for (int c0 = 0; c0 < Cd; c0 += 32) {
#pragma unroll
        for (int p = 0; p < 2; ++p) {
            int i = t + p * 256;
            int c = i >> 4;
            int n4 = (i & 15) * 4;
            float4 x = *(const float4*)(Xb + (size_t)(c0 + c) * Nx + n0 + n4);
            Xs[n4 + 0][c] = (short)f2b(x.x); Xs[n4 + 1][c] = (short)f2b(x.y);
            Xs[n4 + 2][c] = (short)f2b(x.z); Xs[n4 + 3][c] = (short)f2b(x.w);
        }
        union { unsigned short h[8]; s8v s; } af;
        {
            float4 wa = *(const float4*)(Wrow + c0 + quad * 8);
            float4 wb = *(const float4*)(Wrow + c0 + quad * 8 + 4);
            af.h[0] = f2b(wa.x); af.h[1] = f2b(wa.y); af.h[2] = f2b(wa.z); af.h[3] = f2b(wa.w);
            af.h[4] = f2b(wb.x); af.h[5] = f2b(wb.y); af.h[6] = f2b(wb.z); af.h[7] = f2b(wb.w);
        }
        __syncthreads();
#pragma unroll
        for (int nt = 0; nt < 4; ++nt) {
            s8v bf = *(const s8v*)(&Xs[nt * 16 + lq][quad * 8]);
            acc[nt] = mfma16(af.s, bf, acc[nt]);
        }
        __syncthreads();
    }

    if (MODE == 0) {
#pragma unroll
        for (int nt = 0; nt < 4; ++nt)
#pragma unroll
            for (int r = 0; r < 4; ++r) {
                int o = o0 + w * 16 + quad * 4 + r;
                int n = n0 + nt * 16 + lq;
                Yf[((size_t)b * Cd + o) * Nx + n] = acc[nt][r];
            }
    } else {
#pragma unroll
        for (int nt = 0; nt < 4; ++nt) {
#pragma unroll
            for (int r = 0; r < 4; ++r)
                Tt[lq][w * 16 + quad * 4 + r] = (short)f2b(acc[nt][r]);
            __syncthreads();
            int nrow = t >> 4, o4 = (t & 15) * 4;
            ushort4 val = *(const ushort4*)(&Tt[nrow][o4]);
            *(ushort4*)(Yb + ((size_t)b * Nx + n0 + nt * 16 + nrow) * Cd + o0 + o4) = val;
            __syncthreads();
        }
    }
}

// ---------------------------------------------------------------------------
// attn_f: fused Q-projection + skip-projection + flash attention.
// Round 9 = round 7 (proven 191us) + pair-c u32 staging (proven round 8:
// bank conflicts 5.4M->3.6M). Skip handling REVERTED to round 7: prologue
// stores skip to out, epilogue RMW-adds O/l. Round 8's register-resident
// skip caused scratch spills (FETCH +68MB, dur 191->271) — do not re-try
// without headroom verification.
// ---------------------------------------------------------------------------
__global__ __launch_bounds__(512, 2) void attn_f(const float* __restrict__ up,
                                                 const unsigned short* __restrict__ Wf,
                                                 const unsigned short* __restrict__ Kf,
                                                 const unsigned short* __restrict__ Vf,
                                                 float* __restrict__ out) {
    __shared__ __align__(16) unsigned char Ls[104192];
    unsigned char* Lq = Ls;                                   // Xu then Q: 64x512 bf16 swizzled (65536)
    unsigned short* Pb = (unsigned short*)(Ls + 65536);       // [64][264] bf16 (33792)
    float* pmaxS  = (float*)(Ls + 99328);                     // [64][8]
    float* psumS  = (float*)(Ls + 101376);                    // [64][8]
    float* muS    = (float*)(Ls + 103424);                    // [64]
    float* ssumS  = (float*)(Ls + 103680);                    // [64]
    float* alphaS = (float*)(Ls + 103936);                    // [64]
    float* OtA    = (float*)Ls;                               // epilogue alias [8][32][36] f32

    const int t = threadIdx.x;
    const int l = t & 63, w = t >> 6;          // 8 waves
    const int lcol = l & 31, lhalf = l >> 5;
    const int lq = l & 15, quad = (l >> 4) & 3;
    const int bid = blockIdx.x;
    const int b = bid & 7, n0 = (bid >> 3) * 64;

    // ---- (1) stage up rows -> Xu bf16 swizzled (pair-c u32 writes) ----
    {
        const float* ub = up + (size_t)b * Cd * Nn + n0;
#pragma unroll
        for (int it = 0; it < 8; ++it) {
            int u = it * 512 + t;              // 4096 units: 256 c2 x 16 n4-groups
            int c2 = u >> 4, n4 = (u & 15) * 4;
            float4 a = *(const float4*)(ub + (size_t)(2 * c2) * Nn + n4);
            float4 c = *(const float4*)(ub + (size_t)(2 * c2 + 1) * Nn + n4);
            int cu = c2 >> 2, sb = (c2 & 3) * 4;
            float av[4] = {a.x, a.y, a.z, a.w};
            float cv[4] = {c.x, c.y, c.z, c.w};
#pragma unroll
            for (int j = 0; j < 4; ++j) {
                int n = n4 + j;
                *(unsigned int*)(Lq + ((n * 64 + (cu ^ (n & 15))) << 4) + sb) = f2b2(av[j], cv[j]);
            }
        }
    }
    __syncthreads();

    // ---- (2) Q + skip prologue: wave w owns o = w*64 .. w*64+63 ----
    {
        v4f aq[4][4], ask[4][4];
#pragma unroll
        for (int oi = 0; oi < 4; ++oi)
#pragma unroll
            for (int ni = 0; ni < 4; ++ni) {
                aq[oi][ni] = (v4f){0.f, 0.f, 0.f, 0.f};
                ask[oi][ni] = (v4f){0.f, 0.f, 0.f, 0.f};
            }
        const unsigned short* WqF = Wf + (size_t)l * 8;                    // Wf[0] = Wq
        const unsigned short* WsF = Wf + (size_t)3 * 262144 + (size_t)l * 8;  // Wf[3] = Wskip
        for (int step = 0; step < 16; ++step) {
            s8v a1[4], a2[4];
#pragma unroll
            for (int oi = 0; oi < 4; ++oi)
                a1[oi] = *(const s8v*)(WqF + ((size_t)((w * 4 + oi) * 16 + step) << 9));
#pragma unroll
            for (int oi = 0; oi < 4; ++oi)
                a2[oi] = *(const s8v*)(WsF + ((size_t)((w * 4 + oi) * 16 + step) << 9));
#pragma unroll
            for (int ni = 0; ni < 4; ++ni) {
                int n = ni * 16 + lq;          // n&15 == lq
                s8v bf = *(const s8v*)(Lq + ((n * 64 + ((step * 4 + quad) ^ lq)) << 4));
#pragma unroll
                for (int oi = 0; oi < 4; ++oi) {
                    aq[oi][ni] = mfma16(a1[oi], bf, aq[oi][ni]);
                    ask[oi][ni] = mfma16(a2[oi], bf, ask[oi][ni]);
                }
            }
        }
        // skip -> out (pure store; epilogue RMW-adds attention on top)
#pragma unroll
        for (int oi = 0; oi < 4; ++oi)
#pragma unroll
            for (int ni = 0; ni < 4; ++ni)
#pragma unroll
                for (int r = 0; r < 4; ++r) {
                    int o = w * 64 + oi * 16 + quad * 4 + r;
                    int n = n0 + ni * 16 + lq;
                    out[((size_t)b * Cd + o) * Nn + n] = ask[oi][ni][r];
                }
        __syncthreads();   // all Xu reads complete before overwrite
        // Q -> Lq (overwrite Xu), swizzled bf16, 8B per (oi,ni)
#pragma unroll
        for (int oi = 0; oi < 4; ++oi)
#pragma unroll
            for (int ni = 0; ni < 4; ++ni) {
                int n = ni * 16 + lq;
                int cu = w * 8 + oi * 2 + (quad >> 1);
                ushort4 pk;
                pk.x = f2b(aq[oi][ni][0]); pk.y = f2b(aq[oi][ni][1]);
                pk.z = f2b(aq[oi][ni][2]); pk.w = f2b(aq[oi][ni][3]);
                *(ushort4*)(Lq + ((n * 64 + (cu ^ lq)) << 4) + (quad & 1) * 8) = pk;
            }
    }
    if (t < 64) { muS[t] = -1e30f; ssumS[t] = 0.f; }

    v16f o_acc[2][2];
#pragma unroll
    for (int nh = 0; nh < 2; ++nh)
#pragma unroll
        for (int ti = 0; ti < 2; ++ti)
#pragma unroll
            for (int r = 0; r < 16; ++r) o_acc[nh][ti][r] = 0.f;
    __syncthreads();

    const unsigned short* Kfb = Kf + (size_t)b * Mm * Cd + (size_t)l * 8;
    const unsigned short* Vfb = Vf + (size_t)b * Cd * Mm + (size_t)l * 8;
    const int q0 = lcol * 64, q1 = (lcol + 32) * 64;
    const int swz = lcol & 15;
    const float sc = 0.04419417382415922f;   // 1/sqrt(512)

    for (int m0 = 0; m0 < Mm; m0 += 256) {
        v16f st0, st1;
#pragma unroll
        for (int r = 0; r < 16; ++r) { st0[r] = 0.f; st1[r] = 0.f; }
        const unsigned short* kp = Kfb + (size_t)(((m0 >> 5) + w) * 32) * 512;
#pragma unroll
        for (int kb8 = 0; kb8 < 4; ++kb8) {
            uint4 ka[8];
#pragma unroll
            for (int j = 0; j < 8; ++j) ka[j] = *(const uint4*)(kp + (size_t)(kb8 * 8 + j) * 512);
            __builtin_amdgcn_s_setprio(1);
#pragma unroll
            for (int j = 0; j < 8; ++j) {
                int kb = kb8 * 8 + j;
                int uo = (kb * 2 + lhalf) ^ swz;
                s8v qf0 = *(const s8v*)(Lq + ((q0 + uo) << 4));
                s8v qf1 = *(const s8v*)(Lq + ((q1 + uo) << 4));
                union { uint4 u; s8v s; } av; av.u = ka[j];
                st0 = mfma32(av.s, qf0, st0);
                st1 = mfma32(av.s, qf1, st1);
            }
            __builtin_amdgcn_s_setprio(0);
        }
        uint4 v0p[8];
        {
            const unsigned short* vc = Vfb + (size_t)((w * 2) * 64 + (m0 >> 4)) * 512;
#pragma unroll
            for (int j = 0; j < 8; ++j) v0p[j] = *(const uint4*)(vc + (size_t)j * 512);
        }
#pragma unroll
        for (int r = 0; r < 16; ++r) { st0[r] *= sc; st1[r] *= sc; }
        float tm0 = st0[0], tm1 = st1[0];
#pragma unroll
        for (int r = 1; r < 16; ++r) { tm0 = fmaxf(tm0, st0[r]); tm1 = fmaxf(tm1, st1[r]); }
        tm0 = fmaxf(tm0, __shfl_xor(tm0, 32));
        tm1 = fmaxf(tm1, __shfl_xor(tm1, 32));
        if (l < 32) {
            pmaxS[l * 8 + w] = tm0;
            pmaxS[(l + 32) * 8 + w] = tm1;
        }
        __syncthreads();   // S1
        {
            int row = t >> 3, p = t & 7;
            float v = pmaxS[row * 8 + p];
            v = fmaxf(v, __shfl_xor(v, 1));
            v = fmaxf(v, __shfl_xor(v, 2));
            v = fmaxf(v, __shfl_xor(v, 4));
            if (p == 0) {
                float mold = muS[row];
                float mx = fmaxf(mold, v);
                alphaS[row] = __expf(mold - mx);
                muS[row] = mx;
            }
        }
        __syncthreads();   // S2
        {
            float mx0 = muS[lcol], mx1 = muS[lcol + 32];
            float e0[16], e1[16], rs0 = 0.f, rs1 = 0.f;
#pragma unroll
            for (int r = 0; r < 16; ++r) {
                e0[r] = __expf(st0[r] - mx0); rs0 += e0[r];
                e1[r] = __expf(st1[r] - mx1); rs1 += e1[r];
            }
            rs0 += __shfl_xor(rs0, 32);
            rs1 += __shfl_xor(rs1, 32);
            if (l < 32) {
                psumS[l * 8 + w] = rs0;
                psumS[(l + 32) * 8 + w] = rs1;
            }
#pragma unroll
            for (int rg = 0; rg < 4; ++rg) {
                ushort4 pk0, pk1;
                pk0.x = f2b(e0[rg * 4 + 0]); pk0.y = f2b(e0[rg * 4 + 1]);
                pk0.z = f2b(e0[rg * 4 + 2]); pk0.w = f2b(e0[rg * 4 + 3]);
                pk1.x = f2b(e1[rg * 4 + 0]); pk1.y = f2b(e1[rg * 4 + 1]);
                pk1.z = f2b(e1[rg * 4 + 2]); pk1.w = f2b(e1[rg * 4 + 3]);
                *(ushort4*)(Pb + lcol * 264 + w * 32 + 8 * rg + 4 * lhalf) = pk0;
                *(ushort4*)(Pb + (lcol + 32) * 264 + w * 32 + 8 * rg + 4 * lhalf) = pk1;
            }
        }
        __syncthreads();   // S3
        {
            int row = t >> 3, p = t & 7;
            float v = psumS[row * 8 + p];
            v += __shfl_xor(v, 1);
            v += __shfl_xor(v, 2);
            v += __shfl_xor(v, 4);
            if (p == 0) ssumS[row] = ssumS[row] * alphaS[row] + v;
        }

        float ar0[16], ar1[16];
#pragma unroll
        for (int r = 0; r < 16; ++r) {
            int crow = (r & 3) + 8 * (r >> 2) + 4 * lhalf;
            ar0[r] = alphaS[crow];
            ar1[r] = alphaS[32 + crow];
        }
#pragma unroll
        for (int ti = 0; ti < 2; ++ti)
#pragma unroll
            for (int r = 0; r < 16; ++r) {
                o_acc[0][ti][r] *= ar0[r];
                o_acc[1][ti][r] *= ar1[r];
            }

#pragma unroll
        for (int h = 0; h < 2; ++h) {
            s8v pA0[8], pA1[8];
#pragma unroll
            for (int j = 0; j < 8; ++j) {
                pA0[j] = *(const s8v*)(Pb + lcol * 264 + (h * 8 + j) * 16 + lhalf * 8);
                pA1[j] = *(const s8v*)(Pb + (lcol + 32) * 264 + (h * 8 + j) * 16 + lhalf * 8);
            }
#pragma unroll
            for (int ti = 0; ti < 2; ++ti) {
                uint4 vb[8];
                if (h == 0 && ti == 0) {
#pragma unroll
                    for (int j = 0; j < 8; ++j) vb[j] = v0p[j];
                } else {
                    const unsigned short* vc = Vfb + (size_t)((w * 2 + ti) * 64 + (m0 >> 4) + h * 8) * 512;
#pragma unroll
                    for (int j = 0; j < 8; ++j) vb[j] = *(const uint4*)(vc + (size_t)j * 512);
                }
                __builtin_amdgcn_s_setprio(1);
#pragma unroll
                for (int j = 0; j < 8; ++j) {
                    union { uint4 u; s8v s; } bv; bv.u = vb[j];
                    o_acc[0][ti] = mfma32(pA0[j], bv.s, o_acc[0][ti]);
                    o_acc[1][ti] = mfma32(pA1[j], bv.s, o_acc[1][ti]);
                }
                __builtin_amdgcn_s_setprio(0);
            }
        }
        __syncthreads();
    }

    // ---- epilogue: out[b][c][n0..n0+63] += O / l (RMW over prologue skip) ----
    float inv0[16], inv1[16];
#pragma unroll
    for (int r = 0; r < 16; ++r) {
        int crow = (r & 3) + 8 * (r >> 2) + 4 * lhalf;
        inv0[r] = 1.0f / ssumS[crow];
        inv1[r] = 1.0f / ssumS[32 + crow];
    }
    float* OtW = OtA + w * 32 * 36;
#pragma unroll
    for (int nh = 0; nh < 2; ++nh)
#pragma unroll
        for (int ti = 0; ti < 2; ++ti) {
#pragma unroll
            for (int r = 0; r < 16; ++r) {
                int crow = (r & 3) + 8 * (r >> 2) + 4 * lhalf;
                OtW[lcol * 36 + crow] = o_acc[nh][ti][r] * (nh ? inv1[r] : inv0[r]);
            }
            // same-wave LDS ordering -> no barrier needed
            int cloc = l >> 1, half = l & 1;
            int cabs = (w * 2 + ti) * 32 + cloc;
            const float* src = OtW + cloc * 36 + half * 16;
            float* op = out + ((size_t)b * Cd + cabs) * Nn + n0 + nh * 32 + half * 16;
#pragma unroll
            for (int j = 0; j < 4; ++j) {
                float4 a = *(const float4*)(src + j * 4);
                float4 g = *(const float4*)(op + j * 4);
                g.x += a.x; g.y += a.y; g.z += a.z; g.w += a.w;
                *(float4*)(op + j * 4) = g;
            }
        }
}

// ---------------------------------------------------------------------------
// Fallback VALU attention (proven) for small ws_size.
// ---------------------------------------------------------------------------
__device__ __forceinline__ float u2lo(unsigned int u) {
    union { unsigned int i; float f; } v; v.i = u << 16; return v.f;
}
__device__ __forceinline__ float u2hi(unsigned int u) {
    union { unsigned int i; float f; } v; v.i = u & 0xFFFF0000u; return v.f;
}

__global__ __launch_bounds__(256) void attn_k(const float* __restrict__ up,
                                              const float* __restrict__ Wq,
                                              const unsigned short* __restrict__ Ktb,
                                              const unsigned short* __restrict__ Vtb,
                                              float* __restrict__ out) {
    __shared__ float Qs[16][516];
    __shared__ __align__(16) unsigned char Sraw[24576];
    unsigned short (*Us)[16]  = reinterpret_cast<unsigned short(*)[16]>(Sraw);
    unsigned short (*Wt)[512] = reinterpret_cast<unsigned short(*)[512]>(Sraw + 16384);
    float (*Ps)[65] = reinterpret_cast<float(*)[65]>(Sraw);
    float* mu_s     = reinterpret_cast<float*>(Sraw + 4160);
    float* ssum_s   = reinterpret_cast<float*>(Sraw + 4224);
    float* alpha_s  = reinterpret_cast<float*>(Sraw + 4288);

    const int t = threadIdx.x;
    const int b = blockIdx.y;
    const int n0 = blockIdx.x * 16;
    const int row = t & 15;
    const int grp = t >> 4;

    for (int i = t; i < Cd * 16; i += 256) {
        int c = i >> 4, r = i & 15;
        Us[c][r] = f2b(up[((size_t)b * Cd + c) * Nn + n0 + r]);
    }
    __syncthreads();

    float acc[32];
#pragma unroll
    for (int j = 0; j < 32; ++j) acc[j] = 0.f;

    for (int k0 = 0; k0 < Cd; k0 += 8) {
        for (int i = t; i < 1024; i += 256) {
            int oc = i >> 1;
            int kc = (i & 1) * 4;
            float4 wv = *(const float4*)(Wq + (size_t)oc * Cd + k0 + kc);
            Wt[kc + 0][oc] = f2b(wv.x); Wt[kc + 1][oc] = f2b(wv.y);
            Wt[kc + 2][oc] = f2b(wv.z); Wt[kc + 3][oc] = f2b(wv.w);
        }
        __syncthreads();
#pragma unroll
        for (int k = 0; k < 8; ++k) {
            float u = b2f(Us[k0 + k][row]);
            const ushort4* wr = (const ushort4*)(&Wt[k][grp * 32]);
#pragma unroll
            for (int j4 = 0; j4 < 8; ++j4) {
                ushort4 wv = wr[j4];
                acc[j4 * 4 + 0] += u * b2f(wv.x);
                acc[j4 * 4 + 1] += u * b2f(wv.y);
                acc[j4 * 4 + 2] += u * b2f(wv.z);
                acc[j4 * 4 + 3] += u * b2f(wv.w);
            }
        }
        __syncthreads();
    }

    const float scale = 0.04419417382415922f;
#pragma unroll
    for (int j = 0; j < 32; ++j) Qs[row][grp * 32 + j] = acc[j] * scale;
    if (t < 16) { mu_s[t] = -1e30f; ssum_s[t] = 0.f; }
#pragma unroll
    for (int j = 0; j < 32; ++j) acc[j] = 0.f;
    __syncthreads();

    const float4* qr = (const float4*)(&Qs[row][0]);

    for (int m0 = 0; m0 < Mm; m0 += 64) {
        {
            int mb = m0 + grp * 4;
            const uint4* K0 = (const uint4*)(Ktb + ((size_t)b * Mm + mb + 0) * Cd);
            const uint4* K1 = (const uint4*)(Ktb + ((size_t)b * Mm + mb + 1) * Cd);
            const uint4* K2 = (const uint4*)(Ktb + ((size_t)b * Mm + mb + 2) * Cd);
            const uint4* K3 = (const uint4*)(Ktb + ((size_t)b * Mm + mb + 3) * Cd);
            float a0 = 0.f, a1 = 0.f, a2 = 0.f, a3 = 0.f;
#pragma unroll 4
            for (int c8 = 0; c8 < Cd / 8; ++c8) {
                float4 qa = qr[2 * c8], qb = qr[2 * c8 + 1];
                uint4 k0v = K0[c8], k1v = K1[c8], k2v = K2[c8], k3v = K3[c8];
                a0 += qa.x * u2lo(k0v.x) + qa.y * u2hi(k0v.x) + qa.z * u2lo(k0v.y) + qa.w * u2hi(k0v.y)
                    + qb.x * u2lo(k0v.z) + qb.y * u2hi(k0v.z) + qb.z * u2lo(k0v.w) + qb.w * u2hi(k0v.w);
                a1 += qa.x * u2lo(k1v.x) + qa.y * u2hi(k1v.x) + qa.z * u2lo(k1v.y) + qa.w * u2hi(k1v.y)
                    + qb.x * u2lo(k1v.z) + qb.y * u2hi(k1v.z) + qb.z * u2lo(k1v.w) + qb.w * u2hi(k1v.w);
                a2 += qa.x * u2lo(k2v.x) + qa.y * u2hi(k2v.x) + qa.z * u2lo(k2v.y) + qa.w * u2hi(k2v.y)
                    + qb.x * u2lo(k2v.z) + qb.y * u2hi(k2v.z) + qb.z * u2lo(k2v.w) + qb.w * u2hi(k2v.w);
                a3 += qa.x * u2lo(k3v.x) + qa.y * u2hi(k3v.x) + qa.z * u2lo(k3v.y) + qa.w * u2hi(k3v.y)
                    + qb.x * u2lo(k3v.z) + qb.y * u2hi(k3v.z) + qb.z * u2lo(k3v.w) + qb.w * u2hi(k3v.w);
            }
            Ps[row][grp * 4 + 0] = a0;
            Ps[row][grp * 4 + 1] = a1;
            Ps[row][grp * 4 + 2] = a2;
            Ps[row][grp * 4 + 3] = a3;
        }
        __syncthreads();
        if (t < 16) {
            float mold = mu_s[t];
            float mx = mold;
            for (int m = 0; m < 64; ++m) mx = fmaxf(mx, Ps[t][m]);
            float al = __expf(mold - mx);
            float s = ssum_s[t] * al;
            for (int m = 0; m < 64; ++m) {
                float p = __expf(Ps[t][m] - mx);
                Ps[t][m] = p;
                s += p;
            }
            mu_s[t] = mx; ssum_s[t] = s; alpha_s[t] = al;
        }
        __syncthreads();
        {
            float arr = alpha_s[row];
#pragma unroll
            for (int j = 0; j < 32; ++j) acc[j] *= arr;
            const unsigned short* Vbase = Vtb + (size_t)b * Mm * Cd + (size_t)grp * 32;
            for (int m = 0; m < 64; ++m) {
                float p = Ps[row][m];
                const uint4* vr = (const uint4*)(Vbase + (size_t)(m0 + m) * Cd);
#pragma unroll
                for (int j4 = 0; j4 < 4; ++j4) {
                    uint4 v = vr[j4];
                    acc[j4 * 8 + 0] += p * u2lo(v.x); acc[j4 * 8 + 1] += p * u2hi(v.x);
                    acc[j4 * 8 + 2] += p * u2lo(v.y); acc[j4 * 8 + 3] += p * u2hi(v.y);
                    acc[j4 * 8 + 4] += p * u2lo(v.z); acc[j4 * 8 + 5] += p * u2hi(v.z);
                    acc[j4 * 8 + 6] += p * u2lo(v.w); acc[j4 * 8 + 7] += p * u2hi(v.w);
                }
            }
        }
        __syncthreads();
    }

    float invv = 1.0f / ssum_s[row];
#pragma unroll
    for (int j = 0; j < 32; ++j) {
        int c = grp * 32 + j;
        size_t idx = ((size_t)b * Cd + c) * Nn + n0 + row;
        out[idx] = out[idx] + acc[j] * invv;
    }
}

// ---------------------------------------------------------------------------
extern "C" void kernel_launch(void* const* d_in, const int* in_sizes, int n_in,
                              void* d_out, int out_size, void* d_ws, size_t ws_size,
                              hipStream_t stream) {
    const float* up   = (const float*)d_in[0];
    const float* down = (const float*)d_in[1];
    const float* Wq   = (const float*)d_in[2];
    const float* Wk   = (const float*)d_in[3];
    const float* Wv   = (const float*)d_in[4];
    const float* Wsk  = (const float*)d_in[5];
    float* out = (float*)d_out;

    const size_t szK = (size_t)Bn * Mm * Cd;   // 4M bf16 elems (8 MiB)
    const size_t szW = (size_t)4 * Cd * Cd;    // 1M elems (2 MiB)

    if (ws_size >= (2 * szK + szW) * 2) {
        // 18 MiB path, 3 dispatches:
        // convwf -> gemm_kv (fused transpose+K/V) -> attn_f (Q+skip+attention).
        unsigned short* Kf = (unsigned short*)d_ws;
        unsigned short* Vf = Kf + szK;
        unsigned short* Wf = Vf + szK;
        convwf<<<dim3(32, 4), 256, 0, stream>>>(Wq, Wk, Wv, Wsk, Wf);
        gemm_kv<<<dim3(Bn * (Mm / 32) * 2), 256, 0, stream>>>(Wf, down, Kf, Vf);
        attn_f<<<dim3((Nn / 64) * Bn), 512, 0, stream>>>(up, Wf, Kf, Vf, out);
    } else {
        // Fallback (16 MiB ws): VALU attention.
        unsigned short* Ktb = (unsigned short*)d_ws;
        unsigned short* Vtb = Ktb + szK;
        gemm_mfma<2><<<dim3(Mm / 64, Cd / 64, Bn), 256, 0, stream>>>(Wk, down, nullptr, Ktb, Mm);
        gemm_mfma<2><<<dim3(Mm / 64, Cd / 64, Bn), 256, 0, stream>>>(Wv, down, nullptr, Vtb, Mm);
        gemm_mfma<0><<<dim3(Nn / 64, Cd / 64, Bn), 256, 0, stream>>>(Wsk, up, out, nullptr, Nn);
        attn_k<<<dim3(Nn / 16, Bn), 256, 0, stream>>>(up, Wq, Ktb, Vtb, out);
    }
}